// Round 1
// baseline (1353.195 us; speedup 1.0000x reference)
//
#include <hip/hip_runtime.h>
#include <cmath>

#define T_ 512
#define B_ 32
#define S_ 512
#define D_ 512
#define D3_ 1536
static constexpr float LN_EPS = 1e-6f;
static constexpr float RSQRT_D = 0.044194173824159216f; // 1/sqrt(512)

// ---------------- block reductions (blockDim == 256 = 4 waves) ----------------
__device__ __forceinline__ float blk_sum(float v, float* sm) {
    v += __shfl_down(v, 32); v += __shfl_down(v, 16); v += __shfl_down(v, 8);
    v += __shfl_down(v, 4);  v += __shfl_down(v, 2);  v += __shfl_down(v, 1);
    int w = threadIdx.x >> 6;
    if ((threadIdx.x & 63) == 0) sm[w] = v;
    __syncthreads();
    float r = sm[0] + sm[1] + sm[2] + sm[3];
    __syncthreads();
    return r;
}

__device__ __forceinline__ float blk_max(float v, float* sm) {
    v = fmaxf(v, __shfl_down(v, 32)); v = fmaxf(v, __shfl_down(v, 16));
    v = fmaxf(v, __shfl_down(v, 8));  v = fmaxf(v, __shfl_down(v, 4));
    v = fmaxf(v, __shfl_down(v, 2));  v = fmaxf(v, __shfl_down(v, 1));
    int w = threadIdx.x >> 6;
    if ((threadIdx.x & 63) == 0) sm[w] = v;
    __syncthreads();
    float r = fmaxf(fmaxf(sm[0], sm[1]), fmaxf(sm[2], sm[3]));
    __syncthreads();
    return r;
}

// ---------------- generic tiled fp32 GEMM, 64x64 tile, BK=16 ----------------
// NT=false: C[m,n] = alpha * sum_k A[m*lda+k] * B[k*ldb+n]
// NT=true : C[m,n] = alpha * sum_k A[m*lda+k] * B[n*ldb+k]
// batched via blockIdx.z with element strides Abs/Bbs/Cbs.
// All dims assumed multiples of 64 (true here: M,N,K in {512,1536,16384}).
template <bool NT>
__global__ __launch_bounds__(256) void gemm64(
    const float* __restrict__ A, int lda, long Abs,
    const float* __restrict__ B, int ldb, long Bbs,
    float* __restrict__ C, int ldc, long Cbs,
    int K, float alpha)
{
    const int bz = blockIdx.z;
    A += (long)bz * Abs; B += (long)bz * Bbs; C += (long)bz * Cbs;
    const int bm = blockIdx.y * 64, bn = blockIdx.x * 64;

    __shared__ float As[16][68];
    __shared__ float Bs[16][68];

    const int tid = threadIdx.x;
    const int tm = (tid >> 4) * 4;   // 0..60
    const int tn = (tid & 15) * 4;   // 0..60

    float acc[4][4];
#pragma unroll
    for (int i = 0; i < 4; i++)
#pragma unroll
        for (int j = 0; j < 4; j++) acc[i][j] = 0.f;

    const int lm = tid >> 2;         // 0..63
    const int lk = (tid & 3) * 4;    // 0,4,8,12
    const int bk = tid >> 4;         // 0..15 (NN B load)
    const int bnn = (tid & 15) * 4;  // 0..60

    for (int k0 = 0; k0 < K; k0 += 16) {
        // A tile: 64 rows x 16 k
        {
            float4 v = *(const float4*)(A + (long)(bm + lm) * lda + k0 + lk);
            As[lk + 0][lm] = v.x; As[lk + 1][lm] = v.y;
            As[lk + 2][lm] = v.z; As[lk + 3][lm] = v.w;
        }
        // B tile
        if (!NT) {
            float4 v = *(const float4*)(B + (long)(k0 + bk) * ldb + bn + bnn);
            *(float4*)&Bs[bk][bnn] = v;
        } else {
            float4 v = *(const float4*)(B + (long)(bn + lm) * ldb + k0 + lk);
            Bs[lk + 0][lm] = v.x; Bs[lk + 1][lm] = v.y;
            Bs[lk + 2][lm] = v.z; Bs[lk + 3][lm] = v.w;
        }
        __syncthreads();
#pragma unroll
        for (int k = 0; k < 16; k++) {
            float4 a = *(const float4*)&As[k][tm];
            float4 b = *(const float4*)&Bs[k][tn];
            float av[4] = {a.x, a.y, a.z, a.w};
            float bv[4] = {b.x, b.y, b.z, b.w};
#pragma unroll
            for (int i = 0; i < 4; i++)
#pragma unroll
                for (int j = 0; j < 4; j++) acc[i][j] += av[i] * bv[j];
        }
        __syncthreads();
    }
#pragma unroll
    for (int i = 0; i < 4; i++) {
        float4 r = make_float4(alpha * acc[i][0], alpha * acc[i][1],
                               alpha * acc[i][2], alpha * acc[i][3]);
        *(float4*)(C + (long)(bm + tm + i) * ldc + bn + tn) = r;
    }
}

// ---------------- in-place row LayerNorm (+ optional sigmoid on first cols) --
__global__ __launch_bounds__(256) void ln_rows(
    float* __restrict__ X, const float* __restrict__ g,
    const float* __restrict__ bb, int ncols, int sig_upto)
{
    __shared__ float sm[4];
    float* x = X + (long)blockIdx.x * ncols;
    float s = 0.f, q = 0.f;
    for (int c = threadIdx.x; c < ncols; c += 256) {
        float v = x[c]; s += v; q += v * v;
    }
    s = blk_sum(s, sm);
    q = blk_sum(q, sm);
    float m = s / ncols;
    float rs = rsqrtf(q / ncols - m * m + LN_EPS);
    for (int c = threadIdx.x; c < ncols; c += 256) {
        float v = (x[c] - m) * rs * g[c] + bb[c];
        if (c < sig_upto) v = 1.f / (1.f + __expf(-v));
        x[c] = v;
    }
}

// ---------------- SRU linear recurrence scan -------------------------------
// pre: [T,B,3D] post-LN; cols [0,D)=z(sig), [D,2D)=h_gate(sig), [2D,3D)=pl
__global__ __launch_bounds__(256) void sru_scan(
    const float* __restrict__ pre, const float* __restrict__ h0,
    float* __restrict__ ss, float* __restrict__ hlast)
{
    int idx = blockIdx.x * 256 + threadIdx.x;  // 0..16383 = b*512+d
    int b = idx >> 9, d = idx & 511;
    float s = h0[idx];
    const float* pz = pre + (long)b * D3_ + d;
    for (int t = 0; t < T_; t++) {
        const float* p = pz + (long)t * (B_ * D3_);
        float z = p[0];
        float pl = p[2 * D_];
        s += z * (pl - s);                       // (1-z)*s + z*pl
        ss[(long)t * (B_ * D_) + idx] = s;
    }
    hlast[idx] = s;
}

// ---------------- masked softmax over S, writes p_attn [T,B,S] --------------
__global__ __launch_bounds__(256) void softmax_mask(
    const float* __restrict__ align, const int* __restrict__ mlen,
    float* __restrict__ pattn)
{
    __shared__ float sm[4];
    int b = blockIdx.x >> 9;           // blockIdx = b*T + t
    int t = blockIdx.x & 511;
    const float* arow = align + ((long)b * T_ + t) * S_;
    float* orow = pattn + ((long)t * B_ + b) * S_;
    int len = mlen[b];

    float mx = -INFINITY;
#pragma unroll
    for (int i = 0; i < 2; i++) {
        int s = threadIdx.x + i * 256;
        float v = (s < len) ? arow[s] : -INFINITY;
        mx = fmaxf(mx, v);
    }
    mx = blk_max(mx, sm);

    float e[2];
    float sum = 0.f;
#pragma unroll
    for (int i = 0; i < 2; i++) {
        int s = threadIdx.x + i * 256;
        float v = (s < len) ? __expf(arow[s] - mx) : 0.f;
        e[i] = v; sum += v;
    }
    sum = blk_sum(sum, sm);
    float inv = 1.f / sum;
#pragma unroll
    for (int i = 0; i < 2; i++) {
        int s = threadIdx.x + i * 256;
        orow[s] = e[i] * inv;
    }
}

// ---------------- final: LN(h1)+LN(h2) -> tanh -> highway gate --------------
__global__ __launch_bounds__(256) void final_fuse(
    const float* __restrict__ h1, const float* __restrict__ h2,
    const float* __restrict__ pre, const float* __restrict__ prev,
    const float* __restrict__ g_h, const float* __restrict__ b_h,
    const float* __restrict__ g_c, const float* __restrict__ b_c,
    float* __restrict__ out)
{
    __shared__ float sm[4];
    long row = blockIdx.x;             // t*B+b
    const float* x1 = h1 + row * D_;
    const float* x2 = h2 + row * D_;
    float v1[2], v2[2];
    float s1 = 0, q1 = 0, s2 = 0, q2 = 0;
#pragma unroll
    for (int i = 0; i < 2; i++) {
        int c = threadIdx.x + i * 256;
        float a = x1[c], b = x2[c];
        v1[i] = a; v2[i] = b;
        s1 += a; q1 += a * a; s2 += b; q2 += b * b;
    }
    s1 = blk_sum(s1, sm); q1 = blk_sum(q1, sm);
    s2 = blk_sum(s2, sm); q2 = blk_sum(q2, sm);
    float m1 = s1 / D_, m2 = s2 / D_;
    float rs1 = rsqrtf(q1 / D_ - m1 * m1 + LN_EPS);
    float rs2 = rsqrtf(q2 / D_ - m2 * m2 + LN_EPS);
#pragma unroll
    for (int i = 0; i < 2; i++) {
        int c = threadIdx.x + i * 256;
        float t1 = (v1[i] - m1) * rs1 * g_h[c] + b_h[c];
        float t2 = (v2[i] - m2) * rs2 * g_c[c] + b_c[c];
        float o = tanhf(t1 + t2);
        float hg = pre[row * D3_ + D_ + c];           // h_gate (already sigmoided)
        float pv = prev[row * D_ + c];
        out[row * D_ + c] = (1.f - hg) * o + hg * pv;
    }
}

extern "C" void kernel_launch(void* const* d_in, const int* in_sizes, int n_in,
                              void* d_out, int out_size, void* d_ws, size_t ws_size,
                              hipStream_t stream) {
    const float* prev  = (const float*)d_in[0];   // [T,B,D]
    const float* hid0  = (const float*)d_in[1];   // [B,D]
    const float* enc   = (const float*)d_in[2];   // [B,S,D]
    const int*   mlen  = (const int*)  d_in[3];   // [B]
    const float* W_in  = (const float*)d_in[4];   // [D,3D]
    const float* W_enc = (const float*)d_in[5];   // [D,D]
    const float* W_att = (const float*)d_in[6];
    const float* W_hid = (const float*)d_in[7];
    const float* W_ctx = (const float*)d_in[8];
    const float* g_pre = (const float*)d_in[9];
    const float* b_pre = (const float*)d_in[10];
    const float* g_enc = (const float*)d_in[11];
    const float* b_enc = (const float*)d_in[12];
    const float* g_att = (const float*)d_in[13];
    const float* b_att = (const float*)d_in[14];
    const float* g_h   = (const float*)d_in[15];
    const float* b_h   = (const float*)d_in[16];
    const float* g_c   = (const float*)d_in[17];
    const float* b_c   = (const float*)d_in[18];

    float* out   = (float*)d_out;                     // [T,B,D]
    float* hlast = out + (long)T_ * B_ * D_;          // [B,D]
    float* pattn = hlast + (long)B_ * D_;             // [T,B,S]

    const long R  = (long)T_ * B_;                    // 16384 rows
    float* ws     = (float*)d_ws;
    float* pre    = ws;                               // [R,3D]   96 MB
    float* pctx   = pre    + R * D3_;                 // [B,S,D]  32 MB
    float* ss     = pctx   + R * D_;                  // [T,B,D]  32 MB
    float* attnin = ss     + R * D_;                  // [T,B,D]  32 MB (reused as h1)
    float* algn   = attnin + R * D_;                  // [B,T,S]  32 MB (reused as attn_out)
    float* h2     = algn   + R * D_;                  // [T,B,D]  32 MB

    dim3 blk(256);

    // 1) preact = LN(prev @ W_in), sigmoid on first 2D cols
    gemm64<false><<<dim3(D3_ / 64, R / 64, 1), blk, 0, stream>>>(
        prev, D_, 0, W_in, D3_, 0, pre, D3_, 0, D_, 1.f);
    ln_rows<<<R, blk, 0, stream>>>(pre, g_pre, b_pre, D3_, 2 * D_);

    // 2) pctx = LN(enc @ W_enc)
    gemm64<false><<<dim3(D_ / 64, R / 64, 1), blk, 0, stream>>>(
        enc, D_, 0, W_enc, D_, 0, pctx, D_, 0, D_, 1.f);
    ln_rows<<<R, blk, 0, stream>>>(pctx, g_enc, b_enc, D_, 0);

    // 3) SRU scan -> ss, hidden_last
    sru_scan<<<(B_ * D_) / 256, blk, 0, stream>>>(pre, hid0, ss, hlast);

    // 4) attn_in = LN(ss @ W_attn_in)
    gemm64<false><<<dim3(D_ / 64, R / 64, 1), blk, 0, stream>>>(
        ss, D_, 0, W_att, D_, 0, attnin, D_, 0, D_, 1.f);
    ln_rows<<<R, blk, 0, stream>>>(attnin, g_att, b_att, D_, 0);

    // 5) align[b] = (attn_in_b [T,D]) @ (pctx_b [S,D])^T / sqrt(d)
    gemm64<true><<<dim3(S_ / 64, T_ / 64, B_), blk, 0, stream>>>(
        attnin, B_ * D_, D_, pctx, D_, (long)S_ * D_, algn, S_, (long)T_ * S_,
        D_, RSQRT_D);

    // 6) masked softmax -> p_attn [T,B,S]
    softmax_mask<<<B_ * T_, blk, 0, stream>>>(algn, mlen, pattn);

    // 7) attn_out[b] = (av_b [T,S]) @ (pctx_b [S,D]) / sqrt(d)  (into algn buf)
    gemm64<false><<<dim3(D_ / 64, T_ / 64, B_), blk, 0, stream>>>(
        pattn, B_ * S_, S_, pctx, D_, (long)S_ * D_, algn, B_ * D_, D_,
        S_, RSQRT_D);

    // 8) h1 = ss @ W_hidden (into attnin buf), h2 = attn_out @ W_ctx
    gemm64<false><<<dim3(D_ / 64, R / 64, 1), blk, 0, stream>>>(
        ss, D_, 0, W_hid, D_, 0, attnin, D_, 0, D_, 1.f);
    gemm64<false><<<dim3(D_ / 64, R / 64, 1), blk, 0, stream>>>(
        algn, D_, 0, W_ctx, D_, 0, h2, D_, 0, D_, 1.f);

    // 9) out = (1-h_gate)*tanh(LN(h1)+LN(h2)) + h_gate*prev
    final_fuse<<<R, blk, 0, stream>>>(attnin, h2, pre, prev,
                                      g_h, b_h, g_c, b_c, out);
}

// Round 2
// 504.812 us; speedup vs baseline: 2.6806x; 2.6806x over previous
//
#include <hip/hip_runtime.h>
#include <hip/hip_bf16.h>
#include <cmath>

#define T_ 512
#define B_ 32
#define S_ 512
#define D_ 512
#define D3_ 1536
#define NCH 16
#define CT (T_ / NCH)          // 32 timesteps per scan chunk
static constexpr float LN_EPS = 1e-6f;
static constexpr float RSQRT_D = 0.044194173824159216f; // 1/sqrt(512)

typedef __attribute__((ext_vector_type(8))) __bf16 bf16x8;
typedef __attribute__((ext_vector_type(4))) float f32x4;

struct __align__(4) bfx2 { __hip_bfloat16 x, y; };
struct __align__(8) bfx4 { __hip_bfloat16 x, y, z, w; };

// ---------------- async global->LDS, 16B per lane ---------------------------
__device__ __forceinline__ void g2l16(const void* g, void* l) {
    __builtin_amdgcn_global_load_lds(
        (const __attribute__((address_space(1))) unsigned int*)g,
        (__attribute__((address_space(3))) unsigned int*)l, 16, 0, 0);
}

// ---------------- block reductions (blockDim == 256 = 4 waves) --------------
__device__ __forceinline__ float blk_sum(float v, float* sm) {
    v += __shfl_down(v, 32); v += __shfl_down(v, 16); v += __shfl_down(v, 8);
    v += __shfl_down(v, 4);  v += __shfl_down(v, 2);  v += __shfl_down(v, 1);
    int w = threadIdx.x >> 6;
    if ((threadIdx.x & 63) == 0) sm[w] = v;
    __syncthreads();
    float r = sm[0] + sm[1] + sm[2] + sm[3];
    __syncthreads();
    return r;
}

__device__ __forceinline__ float blk_max(float v, float* sm) {
    v = fmaxf(v, __shfl_down(v, 32)); v = fmaxf(v, __shfl_down(v, 16));
    v = fmaxf(v, __shfl_down(v, 8));  v = fmaxf(v, __shfl_down(v, 4));
    v = fmaxf(v, __shfl_down(v, 2));  v = fmaxf(v, __shfl_down(v, 1));
    int w = threadIdx.x >> 6;
    if ((threadIdx.x & 63) == 0) sm[w] = v;
    __syncthreads();
    float r = fmaxf(fmaxf(sm[0], sm[1]), fmaxf(sm[2], sm[3]));
    __syncthreads();
    return r;
}

// ---------------- bf16 MFMA GEMM (NT form), 128x128 tile, BK=32 -------------
// A: [M,K] bf16 k-contiguous (lda elems), B: [N,K] bf16 k-contiguous (ldb).
// C[m,n] = alpha * sum_k A[m][k]*B[n][k].  Batched via blockIdx.z (elem strides).
// m97 structure: global_load_lds width=16, 4 waves each 64x64 (4x4 MFMA tiles).
template <typename OT>
__global__ __launch_bounds__(256) void gemm_bt(
    const __hip_bfloat16* __restrict__ A, int lda, long Abs,
    const __hip_bfloat16* __restrict__ B, int ldb, long Bbs,
    OT* __restrict__ C, long ldc, long Cbs,
    int K, float alpha)
{
    __shared__ __align__(16) __hip_bfloat16 As[128 * 32];
    __shared__ __align__(16) __hip_bfloat16 Bs[128 * 32];

    const int bz = blockIdx.z;
    A += (long)bz * Abs; B += (long)bz * Bbs; C += (long)bz * Cbs;
    const long bm = (long)blockIdx.y * 128, bn = (long)blockIdx.x * 128;

    const int tid = threadIdx.x, lane = tid & 63, w = tid >> 6;
    const int wm = (w >> 1) * 64, wn = (w & 1) * 64;
    const int srow = lane >> 2;          // row within 16-row chunk
    const int skB = (lane & 3) * 16;     // byte offset within 64B row

    f32x4 acc[4][4];
#pragma unroll
    for (int i = 0; i < 4; i++)
#pragma unroll
        for (int j = 0; j < 4; j++) acc[i][j] = (f32x4)(0.0f);

    // staging: wave w handles chunks {w, w+4} of each 128x32 tile
    const char* ga0 = (const char*)(A + (bm + w * 16 + srow) * (long)lda) + skB;
    const char* ga1 = (const char*)(A + (bm + (w + 4) * 16 + srow) * (long)lda) + skB;
    const char* gb0 = (const char*)(B + (bn + w * 16 + srow) * (long)ldb) + skB;
    const char* gb1 = (const char*)(B + (bn + (w + 4) * 16 + srow) * (long)ldb) + skB;
    char* la0 = (char*)As + w * 1024 + lane * 16;
    char* la1 = (char*)As + (w + 4) * 1024 + lane * 16;
    char* lb0 = (char*)Bs + w * 1024 + lane * 16;
    char* lb1 = (char*)Bs + (w + 4) * 1024 + lane * 16;

    // fragment read addresses (constant over K-loop)
    const char* Ar = (const char*)As + (wm + (lane & 15)) * 64 + (lane >> 4) * 16;
    const char* Br = (const char*)Bs + (wn + (lane & 15)) * 64 + (lane >> 4) * 16;

    for (int k0 = 0; k0 < K; k0 += 32) {
        const long kb = (long)k0 * 2;
        g2l16(ga0 + kb, la0);
        g2l16(ga1 + kb, la1);
        g2l16(gb0 + kb, lb0);
        g2l16(gb1 + kb, lb1);
        __syncthreads();

        bf16x8 af[4], bfr[4];
#pragma unroll
        for (int i = 0; i < 4; i++) {
            af[i] = *(const bf16x8*)(Ar + i * 1024);
            bfr[i] = *(const bf16x8*)(Br + i * 1024);
        }
#pragma unroll
        for (int i = 0; i < 4; i++)
#pragma unroll
            for (int j = 0; j < 4; j++)
                acc[i][j] = __builtin_amdgcn_mfma_f32_16x16x32_bf16(
                    af[i], bfr[j], acc[i][j], 0, 0, 0);
        __syncthreads();
    }

    // epilogue: C/D layout col=lane&15, row=(lane>>4)*4+reg
#pragma unroll
    for (int i = 0; i < 4; i++) {
        const long row0 = bm + wm + i * 16 + (lane >> 4) * 4;
#pragma unroll
        for (int j = 0; j < 4; j++) {
            const long col = bn + wn + j * 16 + (lane & 15);
#pragma unroll
            for (int r = 0; r < 4; r++)
                C[(row0 + r) * ldc + col] = (OT)(alpha * acc[i][j][r]);
        }
    }
}

// ---------------- f32 -> bf16 elementwise (x4 vectorized) -------------------
__global__ __launch_bounds__(256) void cvt4(
    const float* __restrict__ x, __hip_bfloat16* __restrict__ y, int n4)
{
    int i = blockIdx.x * 256 + threadIdx.x;
    if (i >= n4) return;
    float4 v = ((const float4*)x)[i];
    bfx4 o;
    o.x = __float2bfloat16(v.x); o.y = __float2bfloat16(v.y);
    o.z = __float2bfloat16(v.z); o.w = __float2bfloat16(v.w);
    ((bfx4*)y)[i] = o;
}

// ---------------- weight transpose+convert: W[K,N] f32 -> WT[N,K] bf16 ------
__global__ __launch_bounds__(256) void wtrans(
    const float* __restrict__ w0, const float* __restrict__ w1,
    const float* __restrict__ w2, const float* __restrict__ w3,
    const float* __restrict__ w4, __hip_bfloat16* __restrict__ WT)
{
    int z = blockIdx.z;
    const float* W; long off; int N;
    if (z == 0)      { W = w0; off = 0;                N = 1536; }
    else if (z == 1) { W = w1; off = 786432;           N = 512; }
    else if (z == 2) { W = w2; off = 786432 + 262144;  N = 512; }
    else if (z == 3) { W = w3; off = 786432 + 524288;  N = 512; }
    else             { W = w4; off = 786432 + 786432;  N = 512; }
    int n0 = blockIdx.x * 32, k0 = blockIdx.y * 32;
    if (n0 >= N) return;
    __shared__ float t[32][33];
    int tx = threadIdx.x & 31, ty = threadIdx.x >> 5;
#pragma unroll
    for (int i = 0; i < 4; i++)
        t[ty + i * 8][tx] = W[(long)(k0 + ty + i * 8) * N + n0 + tx];
    __syncthreads();
    __hip_bfloat16* O = WT + off;
#pragma unroll
    for (int i = 0; i < 4; i++)
        O[(long)(n0 + ty + i * 8) * 512 + k0 + tx] =
            __float2bfloat16(t[tx][ty + i * 8]);
}

// ---------------- bf16 transpose per batch: [B][S,D] -> [B][D,S] ------------
__global__ __launch_bounds__(256) void ptrans(
    const __hip_bfloat16* __restrict__ src, __hip_bfloat16* __restrict__ dst)
{
    long boff = (long)blockIdx.z * (S_ * D_);
    int d0 = blockIdx.x * 32, s0 = blockIdx.y * 32;
    __shared__ __hip_bfloat16 t[32][34];
    int tx = threadIdx.x & 31, ty = threadIdx.x >> 5;
#pragma unroll
    for (int i = 0; i < 4; i++)
        t[ty + i * 8][tx] = src[boff + (long)(s0 + ty + i * 8) * D_ + d0 + tx];
    __syncthreads();
#pragma unroll
    for (int i = 0; i < 4; i++)
        dst[boff + (long)(d0 + ty + i * 8) * S_ + s0 + tx] = t[tx][ty + i * 8];
}

// ---------------- in-place fp32 row LN (ncols=1536, sigmoid on first 1024) --
__global__ __launch_bounds__(256) void ln_rows(
    float* X, const float* __restrict__ g,
    const float* __restrict__ bb, int ncols, int sig_upto)
{
    __shared__ float sm[4];
    float* x = X + (long)blockIdx.x * ncols;
    float s = 0.f, q = 0.f;
    for (int c = threadIdx.x; c < ncols; c += 256) {
        float v = x[c]; s += v; q += v * v;
    }
    s = blk_sum(s, sm);
    q = blk_sum(q, sm);
    float m = s / ncols;
    float rs = rsqrtf(q / ncols - m * m + LN_EPS);
    for (int c = threadIdx.x; c < ncols; c += 256) {
        float v = (x[c] - m) * rs * g[c] + bb[c];
        if (c < sig_upto) v = 1.f / (1.f + __expf(-v));
        x[c] = v;
    }
}

// ---------------- fp32-in row LN (512 cols) -> bf16 out ---------------------
__global__ __launch_bounds__(256) void ln_bf16(
    const float* __restrict__ X, const float* __restrict__ g,
    const float* __restrict__ bb, __hip_bfloat16* __restrict__ Y)
{
    __shared__ float sm[4];
    const float* x = X + (long)blockIdx.x * 512;
    int c = threadIdx.x * 2;
    float2 v = *(const float2*)(x + c);
    float s = v.x + v.y, q = v.x * v.x + v.y * v.y;
    s = blk_sum(s, sm);
    q = blk_sum(q, sm);
    float m = s * (1.f / 512);
    float rs = rsqrtf(q * (1.f / 512) - m * m + LN_EPS);
    float2 gg = *(const float2*)(g + c);
    float2 bv = *(const float2*)(bb + c);
    bfx2 o;
    o.x = __float2bfloat16((v.x - m) * rs * gg.x + bv.x);
    o.y = __float2bfloat16((v.y - m) * rs * gg.y + bv.y);
    *(bfx2*)(Y + (long)blockIdx.x * 512 + c) = o;
}

// ---------------- chunked SRU scan ------------------------------------------
// s_t = (1-z_t)*s_{t-1} + z_t*pl_t. Chunk-affine: s_out = A*s_in + Bacc.
__global__ __launch_bounds__(256) void scan_part1(
    const float* __restrict__ pre, float* __restrict__ Ap, float* __restrict__ Bp)
{
    int idx = blockIdx.x * 256 + threadIdx.x;   // b*512+d
    int c = blockIdx.y;
    const float* pz = pre + (long)(idx >> 9) * D3_ + (idx & 511);
    float A = 1.f, s = 0.f;
    for (int t = c * CT; t < (c + 1) * CT; t++) {
        const float* p = pz + (long)t * (B_ * D3_);
        float z = p[0], pl = p[2 * D_];
        float a = 1.f - z;
        A *= a;
        s = a * s + z * pl;
    }
    Ap[c * 16384 + idx] = A;
    Bp[c * 16384 + idx] = s;
}

__global__ __launch_bounds__(256) void scan_part2(
    const float* __restrict__ Ap, const float* __restrict__ Bp,
    const float* __restrict__ h0, float* __restrict__ sin_,
    float* __restrict__ hlast)
{
    int idx = blockIdx.x * 256 + threadIdx.x;
    float s = h0[idx];
    for (int c = 0; c < NCH; c++) {
        sin_[c * 16384 + idx] = s;
        s = Ap[c * 16384 + idx] * s + Bp[c * 16384 + idx];
    }
    hlast[idx] = s;
}

__global__ __launch_bounds__(256) void scan_part3(
    const float* __restrict__ pre, const float* __restrict__ sin_,
    __hip_bfloat16* __restrict__ ssb)
{
    int idx = blockIdx.x * 256 + threadIdx.x;
    int c = blockIdx.y;
    float s = sin_[c * 16384 + idx];
    const float* pz = pre + (long)(idx >> 9) * D3_ + (idx & 511);
    for (int t = c * CT; t < (c + 1) * CT; t++) {
        const float* p = pz + (long)t * (B_ * D3_);
        float z = p[0], pl = p[2 * D_];
        s += z * (pl - s);
        ssb[(long)t * 16384 + idx] = __float2bfloat16(s);
    }
}

// ---------------- masked softmax: align[B,T,S] -> pattn fp32 + bf16 [T,B,S] -
__global__ __launch_bounds__(256) void softmax_mask(
    const float* __restrict__ align, const int* __restrict__ mlen,
    float* __restrict__ pattn, __hip_bfloat16* __restrict__ pattnb)
{
    __shared__ float sm[4];
    int b = blockIdx.x >> 9;
    int t = blockIdx.x & 511;
    const float* arow = align + ((long)b * T_ + t) * S_;
    long orow = ((long)t * B_ + b) * S_;
    int len = mlen[b];

    float mx = -INFINITY;
#pragma unroll
    for (int i = 0; i < 2; i++) {
        int s = threadIdx.x + i * 256;
        float v = (s < len) ? arow[s] : -INFINITY;
        mx = fmaxf(mx, v);
    }
    mx = blk_max(mx, sm);

    float e[2];
    float sum = 0.f;
#pragma unroll
    for (int i = 0; i < 2; i++) {
        int s = threadIdx.x + i * 256;
        float v = (s < len) ? __expf(arow[s] - mx) : 0.f;
        e[i] = v; sum += v;
    }
    sum = blk_sum(sum, sm);
    float inv = 1.f / sum;
#pragma unroll
    for (int i = 0; i < 2; i++) {
        int s = threadIdx.x + i * 256;
        float v = e[i] * inv;
        pattn[orow + s] = v;
        pattnb[orow + s] = __float2bfloat16(v);
    }
}

// ---------------- final: LN(h1)+LN(h2) -> tanh -> highway gate --------------
__global__ __launch_bounds__(256) void final_fuse(
    const float* __restrict__ h1, const float* __restrict__ h2,
    const float* __restrict__ pre, const float* __restrict__ prev,
    const float* __restrict__ g_h, const float* __restrict__ b_h,
    const float* __restrict__ g_c, const float* __restrict__ b_c,
    float* __restrict__ out)
{
    __shared__ float sm[4];
    long row = blockIdx.x;
    const float* x1 = h1 + row * D_;
    const float* x2 = h2 + row * D_;
    float v1[2], v2[2];
    float s1 = 0, q1 = 0, s2 = 0, q2 = 0;
#pragma unroll
    for (int i = 0; i < 2; i++) {
        int c = threadIdx.x + i * 256;
        float a = x1[c], b = x2[c];
        v1[i] = a; v2[i] = b;
        s1 += a; q1 += a * a; s2 += b; q2 += b * b;
    }
    s1 = blk_sum(s1, sm); q1 = blk_sum(q1, sm);
    s2 = blk_sum(s2, sm); q2 = blk_sum(q2, sm);
    float m1 = s1 / D_, m2 = s2 / D_;
    float rs1 = rsqrtf(q1 / D_ - m1 * m1 + LN_EPS);
    float rs2 = rsqrtf(q2 / D_ - m2 * m2 + LN_EPS);
#pragma unroll
    for (int i = 0; i < 2; i++) {
        int c = threadIdx.x + i * 256;
        float t1 = (v1[i] - m1) * rs1 * g_h[c] + b_h[c];
        float t2 = (v2[i] - m2) * rs2 * g_c[c] + b_c[c];
        float o = tanhf(t1 + t2);
        float hg = pre[row * D3_ + D_ + c];
        float pv = prev[row * D_ + c];
        out[row * D_ + c] = (1.f - hg) * o + hg * pv;
    }
}

extern "C" void kernel_launch(void* const* d_in, const int* in_sizes, int n_in,
                              void* d_out, int out_size, void* d_ws, size_t ws_size,
                              hipStream_t stream) {
    const float* prev  = (const float*)d_in[0];
    const float* hid0  = (const float*)d_in[1];
    const float* enc   = (const float*)d_in[2];
    const int*   mlen  = (const int*)  d_in[3];
    const float* W_in  = (const float*)d_in[4];
    const float* W_enc = (const float*)d_in[5];
    const float* W_att = (const float*)d_in[6];
    const float* W_hid = (const float*)d_in[7];
    const float* W_ctx = (const float*)d_in[8];
    const float* g_pre = (const float*)d_in[9];
    const float* b_pre = (const float*)d_in[10];
    const float* g_enc = (const float*)d_in[11];
    const float* b_enc = (const float*)d_in[12];
    const float* g_att = (const float*)d_in[13];
    const float* b_att = (const float*)d_in[14];
    const float* g_h   = (const float*)d_in[15];
    const float* b_h   = (const float*)d_in[16];
    const float* g_c   = (const float*)d_in[17];
    const float* b_c   = (const float*)d_in[18];

    float* out   = (float*)d_out;                 // [T,B,D]
    float* hlast = out + (long)T_ * B_ * D_;      // [B,D]
    float* pattn = hlast + (long)B_ * D_;         // [T,B,S]

    // workspace map (MB offsets, lifetimes disjoint where aliased)
    float* ws = (float*)d_ws;
    const long MBf = 262144;                      // floats per MB
    float* pre              = ws;                                   // [0,96)
    __hip_bfloat16* WT      = (__hip_bfloat16*)(ws + 96 * MBf);     // [96,100)
    __hip_bfloat16* prevb   = (__hip_bfloat16*)(ws + 100 * MBf);    // [100,116)
    __hip_bfloat16* encb    = (__hip_bfloat16*)(ws + 116 * MBf);    // [116,132)
    float* pctxf            = ws + 132 * MBf;                       // [132,164)
    __hip_bfloat16* pctxb   = (__hip_bfloat16*)(ws + 164 * MBf);    // [164,180)
    __hip_bfloat16* pctxT   = (__hip_bfloat16*)(ws + 180 * MBf);    // [180,196)
    __hip_bfloat16* ssb     = (__hip_bfloat16*)(ws + 196 * MBf);    // [196,212)
    float* scanA            = ws + 212 * MBf;                       // [212,213)
    float* scanB            = ws + 213 * MBf;                       // [213,214)
    float* sinb             = ws + 214 * MBf;                       // [214,215)
    float* attninf          = ws + 100 * MBf;                       // reuse [100,132)
    __hip_bfloat16* attninb = (__hip_bfloat16*)(ws + 132 * MBf);    // reuse [132,148)
    float* algn             = ws + 212 * MBf;                       // reuse [212,244)
    __hip_bfloat16* pattnb  = (__hip_bfloat16*)(ws + 148 * MBf);    // reuse [148,164)
    __hip_bfloat16* attnoutb= (__hip_bfloat16*)(ws + 100 * MBf);    // reuse [100,116)
    float* h1f              = ws + 116 * MBf;                       // reuse [116,148)
    float* h2f              = ws + 148 * MBf;                       // reuse [148,180)

    const long R = (long)T_ * B_;                 // 16384
    const __hip_bfloat16* W_inT  = WT;
    const __hip_bfloat16* W_encT = WT + 786432;
    const __hip_bfloat16* W_attT = WT + 786432 + 262144;
    const __hip_bfloat16* W_hidT = WT + 786432 + 524288;
    const __hip_bfloat16* W_ctxT = WT + 786432 + 786432;

    dim3 blk(256);

    // inputs -> bf16
    cvt4<<<8192, blk, 0, stream>>>(prev, prevb, (int)(R * D_ / 4));
    cvt4<<<8192, blk, 0, stream>>>(enc, encb, (int)(R * D_ / 4));
    wtrans<<<dim3(48, 16, 5), blk, 0, stream>>>(W_in, W_enc, W_att, W_hid, W_ctx,
                                                (__hip_bfloat16*)WT);

    // 1) pre = prev @ W_in  (fp32 out), then LN + sigmoid on first 2D cols
    gemm_bt<float><<<dim3(12, 128, 1), blk, 0, stream>>>(
        prevb, D_, 0, W_inT, D_, 0, pre, D3_, 0, D_, 1.f);
    ln_rows<<<R, blk, 0, stream>>>(pre, g_pre, b_pre, D3_, 2 * D_);

    // 2) pctx = LN(enc @ W_enc) -> bf16 + transposed bf16
    gemm_bt<float><<<dim3(4, 128, 1), blk, 0, stream>>>(
        encb, D_, 0, W_encT, D_, 0, pctxf, D_, 0, D_, 1.f);
    ln_bf16<<<R, blk, 0, stream>>>(pctxf, g_enc, b_enc, pctxb);
    ptrans<<<dim3(16, 16, 32), blk, 0, stream>>>(pctxb, pctxT);

    // 3) SRU scan (chunked, 3 passes) -> ssb bf16, hlast
    scan_part1<<<dim3(64, NCH), blk, 0, stream>>>(pre, scanA, scanB);
    scan_part2<<<64, blk, 0, stream>>>(scanA, scanB, hid0, sinb, hlast);
    scan_part3<<<dim3(64, NCH), blk, 0, stream>>>(pre, sinb, ssb);

    // 4) attn_in = LN(ss @ W_attn_in) -> bf16
    gemm_bt<float><<<dim3(4, 128, 1), blk, 0, stream>>>(
        ssb, D_, 0, W_attT, D_, 0, attninf, D_, 0, D_, 1.f);
    ln_bf16<<<R, blk, 0, stream>>>(attninf, g_att, b_att, attninb);

    // 5) align[b] = attn_in_b [T,D] @ pctx_b[S,D]^T / sqrt(d)
    gemm_bt<float><<<dim3(4, 4, 32), blk, 0, stream>>>(
        attninb, B_ * D_, D_, pctxb, D_, (long)S_ * D_,
        algn, S_, (long)T_ * S_, D_, RSQRT_D);

    // 6) masked softmax -> pattn (fp32 output) + pattnb (bf16)
    softmax_mask<<<B_ * T_, blk, 0, stream>>>(algn, mlen, pattn, pattnb);

    // 7) attn_out[b] = av_b [T,S] @ pctxT_b [D,S]^T / sqrt(d)  (bf16 out, [T,B,D])
    gemm_bt<__hip_bfloat16><<<dim3(4, 4, 32), blk, 0, stream>>>(
        pattnb, B_ * S_, S_, pctxT, S_, (long)D_ * S_,
        attnoutb, B_ * D_, D_, S_, RSQRT_D);

    // 8) h1 = ss @ W_hidden, h2 = attn_out @ W_ctx (fp32 out)
    gemm_bt<float><<<dim3(4, 128, 1), blk, 0, stream>>>(
        ssb, D_, 0, W_hidT, D_, 0, h1f, D_, 0, D_, 1.f);
    gemm_bt<float><<<dim3(4, 128, 1), blk, 0, stream>>>(
        attnoutb, D_, 0, W_ctxT, D_, 0, h2f, D_, 0, D_, 1.f);

    // 9) out = (1-h_gate)*tanh(LN(h1)+LN(h2)) + h_gate*prev
    final_fuse<<<R, blk, 0, stream>>>(h1f, h2f, pre, prev,
                                      g_h, b_h, g_c, b_c, out);
}